// Round 1
// 421.013 us; speedup vs baseline: 1.1217x; 1.1217x over previous
//
#include <hip/hip_runtime.h>
#include <cstdint>
#include <cstddef>

// Problem constants: B=4, T=827, C=1024, NH=16, HS=64, SCALE=1/8
#define Tn  827
#define Cn  1024
#define BTn 3308      // B*T
#define TPn 832       // T padded to multiple of 32/64
#define YSZ 3387392   // B*T*C  (y output elements)

typedef unsigned short u16;
typedef unsigned short u16x4 __attribute__((ext_vector_type(4)));
typedef __bf16 bf16_t;
typedef bf16_t bf16x8 __attribute__((ext_vector_type(8)));
typedef float f32x4 __attribute__((ext_vector_type(4)));

__device__ inline u16 f32_to_bf16(float f) {
  union { float f; unsigned u; } v; v.f = f;
  unsigned u = v.u;
  u += 0x7fffu + ((u >> 16) & 1u);   // RNE
  return (u16)(u >> 16);
}

// ---------------------------------------------------------------------------
// f32 -> bf16 conversion for x, x_kv, Wq, Wk, Wv, Wp (one fused launch)
// + tail range zeroing Vt pad columns (t = 827..831) so PV never sees poison.
// ---------------------------------------------------------------------------
__global__ __launch_bounds__(256)
void cvt_all_k(const float* __restrict__ x, const float* __restrict__ xkv,
               const float* __restrict__ wq, const float* __restrict__ wk,
               const float* __restrict__ wv, const float* __restrict__ wp,
               u16* __restrict__ xb, u16* __restrict__ xkb,
               u16* __restrict__ wqb, u16* __restrict__ wkb,
               u16* __restrict__ wvb, u16* __restrict__ wpb,
               u16* __restrict__ Vt)
{
  const long NX = 846848;   // YSZ/4
  const long NW = 262144;   // C*C/4
  long qidx = (long)blockIdx.x * 256 + threadIdx.x;
  const float* s; u16* d; long base;
  if (qidx < NX)            { s = x;   d = xb;  base = qidx; }
  else if (qidx < 2 * NX)   { s = xkv; d = xkb; base = qidx - NX; }
  else {
    long w = qidx - 2 * NX;
    int wi = (int)(w / NW);
    if (wi >= 4) {
      // Vt pad zeroing: 4096 rows x 5 cols (t = 827..831)
      long p = w - 4 * NW;          // 0..20479
      if (p < 20480) {
        int row = (int)(p / 5);
        int col = 827 + (int)(p - (long)row * 5);
        Vt[(size_t)row * TPn + col] = 0;
      }
      return;
    }
    base = w - (long)wi * NW;
    if      (wi == 0) { s = wq; d = wqb; }
    else if (wi == 1) { s = wk; d = wkb; }
    else if (wi == 2) { s = wv; d = wvb; }
    else              { s = wp; d = wpb; }
  }
  const float4 v = *(const float4*)(s + base * 4);
  u16x4 o;
  o.x = f32_to_bf16(v.x); o.y = f32_to_bf16(v.y);
  o.z = f32_to_bf16(v.z); o.w = f32_to_bf16(v.w);
  *(u16x4*)(d + base * 4) = o;
}

// ---------------------------------------------------------------------------
// Fused Q/K/V projection GEMM, 128x128 tile, one launch (grid.z = 0/1/2).
//   z==0: Qb = xb.Wq^T + bq      (row-major bf16)
//   z==1: Kb = xkb.Wk^T + bk     (row-major bf16)
//   z==2: Vt = transposed V      (Vt[(b*16+hh)*64+d][t], bf16) -- kills vtrans
// ---------------------------------------------------------------------------
__global__ __launch_bounds__(256)
void gemm_qkv_k(const u16* __restrict__ xb, const u16* __restrict__ xkb,
                const u16* __restrict__ wqb, const u16* __restrict__ wkb,
                const u16* __restrict__ wvb,
                const float* __restrict__ bq, const float* __restrict__ bk,
                const float* __restrict__ bv,
                u16* __restrict__ Qb, u16* __restrict__ Kb, u16* __restrict__ Vt)
{
  const int zz = blockIdx.z;
  const u16* A  = (zz == 0) ? xb : xkb;
  const u16* Bw = (zz == 0) ? wqb : (zz == 1) ? wkb : wvb;
  const float* bias = (zz == 0) ? bq : (zz == 1) ? bk : bv;

  const int tid  = threadIdx.x;
  const int lane = tid & 63;
  const int wave = tid >> 6;
  const int wm = wave >> 1, wn = wave & 1;
  const int m0 = blockIdx.x * 128;
  const int n0 = blockIdx.y * 128;

  __shared__ u16 As[128 * 32];
  __shared__ u16 Bs[128 * 32];

  f32x4 acc[4][4];
  const f32x4 zero4 = {0.f, 0.f, 0.f, 0.f};
  #pragma unroll
  for (int i = 0; i < 4; ++i)
    #pragma unroll
    for (int j = 0; j < 4; ++j)
      acc[i][j] = zero4;

  for (int kt = 0; kt < 32; ++kt) {
    const int k0 = kt << 5;
    __syncthreads();
    #pragma unroll
    for (int it = 0; it < 2; ++it) {
      const int cbase = it * 256 + wave * 64;
      const int c  = cbase + lane;
      const int r  = c >> 2;
      const int ko = (c & 3) << 3;
      if (m0 + r < BTn)
        __builtin_amdgcn_global_load_lds(
            (__attribute__((address_space(1))) void*)(A + (size_t)(m0 + r) * Cn + k0 + ko),
            (__attribute__((address_space(3))) void*)(As + cbase * 8),
            16, 0, 0);
      __builtin_amdgcn_global_load_lds(
          (__attribute__((address_space(1))) void*)(Bw + (size_t)(n0 + r) * Cn + k0 + ko),
          (__attribute__((address_space(3))) void*)(Bs + cbase * 8),
          16, 0, 0);
    }
    __syncthreads();

    bf16x8 af[4], bfr[4];
    #pragma unroll
    for (int i = 0; i < 4; ++i) {
      const int r = wm * 64 + i * 16 + (lane & 15);
      af[i] = *(const bf16x8*)(As + r * 32 + ((lane >> 4) << 3));
    }
    #pragma unroll
    for (int j = 0; j < 4; ++j) {
      const int r = wn * 64 + j * 16 + (lane & 15);
      bfr[j] = *(const bf16x8*)(Bs + r * 32 + ((lane >> 4) << 3));
    }
    #pragma unroll
    for (int i = 0; i < 4; ++i)
      #pragma unroll
      for (int j = 0; j < 4; ++j)
        acc[i][j] = __builtin_amdgcn_mfma_f32_16x16x32_bf16(af[i], bfr[j], acc[i][j], 0, 0, 0);
  }

  const int cq = lane >> 4, cl = lane & 15;
  if (zz < 2) {
    u16* D = (zz == 0) ? Qb : Kb;
    #pragma unroll
    for (int i = 0; i < 4; ++i) {
      #pragma unroll
      for (int j = 0; j < 4; ++j) {
        const int rb  = m0 + wm * 64 + i * 16 + cq * 4;
        const int col = n0 + wn * 64 + j * 16 + cl;
        const float bc = bias[col];
        #pragma unroll
        for (int r = 0; r < 4; ++r) {
          const int row = rb + r;
          if (row < BTn) D[(size_t)row * Cn + col] = f32_to_bf16(acc[i][j][r] + bc);
        }
      }
    }
  } else {
    // V: write transposed into Vt[(b*16+hh)*64+d][t]
    #pragma unroll
    for (int j = 0; j < 4; ++j) {
      const int col = n0 + wn * 64 + j * 16 + cl;
      const int hh = col >> 6, dd = col & 63;
      const float bc = bias[col];
      #pragma unroll
      for (int i = 0; i < 4; ++i) {
        const int rb = m0 + wm * 64 + i * 16 + cq * 4;
        #pragma unroll
        for (int r = 0; r < 4; ++r) {
          const int row = rb + r;
          if (row < BTn) {
            const int bb = row / Tn;
            const int t  = row - bb * Tn;
            Vt[((size_t)((bb * 16 + hh) * 64 + dd)) * TPn + t] = f32_to_bf16(acc[i][j][r] + bc);
          }
        }
      }
    }
  }
}

// ---------------------------------------------------------------------------
// bf16 MFMA GEMM:  C = A(MxK) . B(NxK)^T  (m97 structure, BK=32) -- out proj
// ---------------------------------------------------------------------------
template<int BM, int BN, int MODE>
__global__ __launch_bounds__(256)
void gemm_k(const u16* __restrict__ Aall, const u16* __restrict__ Ball,
            const float* __restrict__ bias, float* __restrict__ Cf,
            u16* __restrict__ Cb, int M, int N, int K, int lda, int ldb, int ldc)
{
  static_assert(BM == 128, "BM fixed at 128");
  constexpr int TM = BM / 32;   // 4
  constexpr int TN = BN / 32;   // 2 (BN=64)

  const int tid  = threadIdx.x;
  const int lane = tid & 63;
  const int wave = tid >> 6;
  const int wm = wave >> 1, wn = wave & 1;
  const int m0 = blockIdx.x * BM;
  const int n0 = blockIdx.y * BN;

  __shared__ u16 As[BM * 32];
  __shared__ u16 Bs[BN * 32];

  f32x4 acc[TM][TN];
  const f32x4 zero4 = {0.f, 0.f, 0.f, 0.f};
  #pragma unroll
  for (int i = 0; i < TM; ++i)
    #pragma unroll
    for (int j = 0; j < TN; ++j)
      acc[i][j] = zero4;

  const int nk = K >> 5;

  for (int kt = 0; kt < nk; ++kt) {
    const int k0 = kt << 5;
    __syncthreads();
    #pragma unroll
    for (int it = 0; it < BM / 64; ++it) {
      const int cbase = it * 256 + wave * 64;
      const int c  = cbase + lane;
      const int r  = c >> 2;
      const int ko = (c & 3) << 3;
      if (m0 + r < M)
        __builtin_amdgcn_global_load_lds(
            (__attribute__((address_space(1))) void*)(Aall + (size_t)(m0 + r) * lda + k0 + ko),
            (__attribute__((address_space(3))) void*)(As + cbase * 8),
            16, 0, 0);
    }
    #pragma unroll
    for (int it = 0; it < BN / 64; ++it) {
      const int cbase = it * 256 + wave * 64;
      const int c  = cbase + lane;
      const int r  = c >> 2;
      const int ko = (c & 3) << 3;
      if (n0 + r < N)
        __builtin_amdgcn_global_load_lds(
            (__attribute__((address_space(1))) void*)(Ball + (size_t)(n0 + r) * ldb + k0 + ko),
            (__attribute__((address_space(3))) void*)(Bs + cbase * 8),
            16, 0, 0);
    }
    __syncthreads();

    bf16x8 af[TM], bfr[TN];
    #pragma unroll
    for (int i = 0; i < TM; ++i) {
      const int r = wm * 64 + i * 16 + (lane & 15);
      af[i] = *(const bf16x8*)(As + r * 32 + ((lane >> 4) << 3));
    }
    #pragma unroll
    for (int j = 0; j < TN; ++j) {
      const int r = wn * (TN * 16) + j * 16 + (lane & 15);
      bfr[j] = *(const bf16x8*)(Bs + r * 32 + ((lane >> 4) << 3));
    }
    #pragma unroll
    for (int i = 0; i < TM; ++i)
      #pragma unroll
      for (int j = 0; j < TN; ++j)
        acc[i][j] = __builtin_amdgcn_mfma_f32_16x16x32_bf16(af[i], bfr[j], acc[i][j], 0, 0, 0);
  }

  const int cq = lane >> 4, cl = lane & 15;
  #pragma unroll
  for (int i = 0; i < TM; ++i) {
    #pragma unroll
    for (int j = 0; j < TN; ++j) {
      const int rb  = m0 + wm * 64 + i * 16 + cq * 4;
      const int col = n0 + wn * (TN * 16) + j * 16 + cl;
      #pragma unroll
      for (int r = 0; r < 4; ++r) {
        const int row = rb + r;
        const float v = acc[i][j][r];
        if constexpr (MODE == 0) {
          if (row < M) Cb[(size_t)row * ldc + col] = f32_to_bf16(v + bias[col]);
        } else {
          if (row < M) Cf[(size_t)row * ldc + col] = v + bias[col];
        }
      }
    }
  }
}

// ---------------------------------------------------------------------------
// b01/b02/b12 -> transposed copies bT[rg*4+b][256][256] with [i][j]=b[b][j][i]
// ---------------------------------------------------------------------------
__global__ __launch_bounds__(256)
void btrans_k(const float* __restrict__ b01, const float* __restrict__ b02,
              const float* __restrict__ b12, float* __restrict__ bT)
{
  const int mb = blockIdx.z;       // rg*4 + b
  const int rg = mb >> 2, bb = mb & 3;
  const float* src = (rg == 0 ? b01 : rg == 1 ? b02 : b12) + (size_t)bb * 65536;
  float* dst = bT + (size_t)mb * 65536;
  const int i0 = blockIdx.x * 64, j0 = blockIdx.y * 64;
  __shared__ float tile[64 * 65];
  const int tid = threadIdx.x;
  #pragma unroll
  for (int rep = 0; rep < 16; ++rep) {
    const int idx = rep * 256 + tid;
    const int jj = idx >> 6, ii = idx & 63;
    tile[ii * 65 + jj] = src[(size_t)(j0 + jj) * 256 + i0 + ii];
  }
  __syncthreads();
  #pragma unroll
  for (int rep = 0; rep < 16; ++rep) {
    const int idx = rep * 256 + tid;
    const int ii = idx >> 6, jj = idx & 63;
    dst[(size_t)(i0 + ii) * 256 + j0 + jj] = tile[ii * 65 + jj];
  }
}

// ---------------------------------------------------------------------------
// FUSED regional kernel (replaces sreg_k + regional_k):
//  per block: 64 q-rows x 256 k-cols of one region:
//    S = Q.K^T * SCALE + h  (MFMA, K=64)
//    softmax(S) -> [rg==2: row stats] -> *= f * bT -> [rg!=0: second softmax]
//    write FINAL logits to Sreg once.
// Each thread holds 4 full rows spread over 16 lanes (16-lane shfl reduces).
// ---------------------------------------------------------------------------
__global__ __launch_bounds__(256)
void regfused_k(const u16* __restrict__ Qb, const u16* __restrict__ Kb,
                const float* __restrict__ hsrc,
                const float* __restrict__ f01, const float* __restrict__ f02,
                const float* __restrict__ f12, const float* __restrict__ bT,
                float* __restrict__ Sreg, float* __restrict__ mmOut,
                float* __restrict__ amOut)
{
  const int zr = blockIdx.y;          // z*3+rg
  const int rg = zr % 3;
  const int z  = zr / 3;
  const int b = z >> 4, hh = z & 15;
  const int qoff = (rg == 0) ? 285 : 571;
  const int koff = (rg == 2) ? 286 : 0;
  const int m0 = blockIdx.x * 64;     // q-chunk base within region (0/64/128/192)

  const int tid = threadIdx.x, lane = tid & 63, wave = tid >> 6;
  const int quad = lane >> 4, cl = lane & 15;

  __shared__ u16 Qs[2 * 2048];        // [panel][64][32]
  __shared__ u16 Ks[2 * 8192];        // [panel][256][32]

  const u16* qsrc = Qb + ((size_t)(b * Tn + qoff + m0)) * Cn + hh * 64;
  const u16* ksrc = Kb + ((size_t)(b * Tn + koff)) * Cn + hh * 64;
  {
    const int r  = tid >> 2;
    const int ko = (tid & 3) << 3;
    #pragma unroll
    for (int p = 0; p < 2; ++p) {
      __builtin_amdgcn_global_load_lds(
          (__attribute__((address_space(1))) void*)(qsrc + (size_t)r * Cn + p * 32 + ko),
          (__attribute__((address_space(3))) void*)(&Qs[p * 2048 + wave * 512]), 16, 0, 0);
      #pragma unroll
      for (int it = 0; it < 4; ++it) {
        const int c  = it * 256 + tid;
        const int rr = c >> 2;
        const int kko = (c & 3) << 3;
        __builtin_amdgcn_global_load_lds(
            (__attribute__((address_space(1))) void*)(ksrc + (size_t)rr * Cn + p * 32 + kko),
            (__attribute__((address_space(3))) void*)(&Ks[p * 8192 + it * 2048 + wave * 512]), 16, 0, 0);
      }
    }
  }
  __syncthreads();

  bf16x8 qa[2];
  #pragma unroll
  for (int p = 0; p < 2; ++p)
    qa[p] = *(const bf16x8*)(&Qs[p * 2048 + (wave * 16 + cl) * 32 + quad * 8]);

  f32x4 acc[16];
  const f32x4 zero4 = {0.f, 0.f, 0.f, 0.f};
  #pragma unroll
  for (int n = 0; n < 16; ++n) acc[n] = zero4;

  #pragma unroll
  for (int p = 0; p < 2; ++p)
    #pragma unroll
    for (int n = 0; n < 16; ++n) {
      const bf16x8 kb = *(const bf16x8*)(&Ks[p * 8192 + (n * 16 + cl) * 32 + quad * 8]);
      acc[n] = __builtin_amdgcn_mfma_f32_16x16x32_bf16(qa[p], kb, acc[n], 0, 0, 0);
    }

  // thread's 4 rows: region rows i0..i0+3 ; cols n*16+cl
  const int i0 = m0 + wave * 16 + quad * 4;
  const float* hp = hsrc + (size_t)z * Tn * Tn + (size_t)(qoff + i0) * Tn + koff + cl;
  #pragma unroll
  for (int nb = 0; nb < 4; ++nb) {
    float hv[4][4];
    #pragma unroll
    for (int n2 = 0; n2 < 4; ++n2)
      #pragma unroll
      for (int r = 0; r < 4; ++r)
        hv[n2][r] = hp[(size_t)r * Tn + (nb * 4 + n2) * 16];
    #pragma unroll
    for (int n2 = 0; n2 < 4; ++n2)
      #pragma unroll
      for (int r = 0; r < 4; ++r)
        acc[nb * 4 + n2][r] = acc[nb * 4 + n2][r] * 0.125f + hv[n2][r];
  }

  // ---- first softmax over 256 cols of each row ----
  float red[4];
  #pragma unroll
  for (int r = 0; r < 4; ++r) {
    float m = acc[0][r];
    #pragma unroll
    for (int n = 1; n < 16; ++n) m = fmaxf(m, acc[n][r]);
    m = fmaxf(m, __shfl_xor(m, 1));
    m = fmaxf(m, __shfl_xor(m, 2));
    m = fmaxf(m, __shfl_xor(m, 4));
    m = fmaxf(m, __shfl_xor(m, 8));
    red[r] = m;
  }
  #pragma unroll
  for (int n = 0; n < 16; ++n)
    #pragma unroll
    for (int r = 0; r < 4; ++r)
      acc[n][r] = __expf(acc[n][r] - red[r]);
  #pragma unroll
  for (int r = 0; r < 4; ++r) {
    float s = 0.f;
    #pragma unroll
    for (int n = 0; n < 16; ++n) s += acc[n][r];
    s += __shfl_xor(s, 1); s += __shfl_xor(s, 2);
    s += __shfl_xor(s, 4); s += __shfl_xor(s, 8);
    const float inv = 1.f / s;
    #pragma unroll
    for (int n = 0; n < 16; ++n) acc[n][r] *= inv;
  }

  // ---- multiply by f * bT, region-2 stats inline ----
  const float* fp  = (rg == 0) ? f01 : (rg == 1) ? f02 : f12;
  const float* fpb = fp + ((size_t)b * 256 + i0) * 256 + cl;
  const float* bpb = bT + (((size_t)(rg * 4 + b)) << 16) + (size_t)i0 * 256 + cl;
  float msum[4] = {0.f, 0.f, 0.f, 0.f};
  float mcnt[4] = {0.f, 0.f, 0.f, 0.f};
  float asum[4] = {0.f, 0.f, 0.f, 0.f};
  #pragma unroll
  for (int nb = 0; nb < 4; ++nb) {
    float fv[4][4], bv[4][4];
    #pragma unroll
    for (int n2 = 0; n2 < 4; ++n2)
      #pragma unroll
      for (int r = 0; r < 4; ++r) {
        fv[n2][r] = fpb[(size_t)r * 256 + (nb * 4 + n2) * 16];
        bv[n2][r] = bpb[(size_t)r * 256 + (nb * 4 + n2) * 16];
      }
    #pragma unroll
    for (int n2 = 0; n2 < 4; ++n2)
      #pragma unroll
      for (int r = 0; r < 4; ++r) {
        const int n = nb * 4 + n2;
        const float prod = fv[n2][r] * bv[n2][r];
        if (rg == 2) {
          const float mk = (prod >= 0.1f) ? 1.f : 0.f;
          msum[r] += acc[n][r] * mk;
          mcnt[r] += mk;
          asum[r] += acc[n][r];
        }
        acc[n][r] *= prod;
      }
  }
  if (rg == 2) {
    #pragma unroll
    for (int r = 0; r < 4; ++r) {
      msum[r] += __shfl_xor(msum[r], 1); msum[r] += __shfl_xor(msum[r], 2);
      msum[r] += __shfl_xor(msum[r], 4); msum[r] += __shfl_xor(msum[r], 8);
      mcnt[r] += __shfl_xor(mcnt[r], 1); mcnt[r] += __shfl_xor(mcnt[r], 2);
      mcnt[r] += __shfl_xor(mcnt[r], 4); mcnt[r] += __shfl_xor(mcnt[r], 8);
      asum[r] += __shfl_xor(asum[r], 1); asum[r] += __shfl_xor(asum[r], 2);
      asum[r] += __shfl_xor(asum[r], 4); asum[r] += __shfl_xor(asum[r], 8);
    }
    if (cl == 0) {
      #pragma unroll
      for (int r = 0; r < 4; ++r) {
        const int idx = ((b * 16 + hh) << 8) + i0 + r;
        mmOut[idx] = msum[r] / mcnt[r];
        amOut[idx] = asum[r] * (1.f / 256.f);
      }
    }
  }

  // ---- region 0: write mult; regions 1/2: second softmax then write ----
  if (rg != 0) {
    #pragma unroll
    for (int r = 0; r < 4; ++r) {
      float m = acc[0][r];
      #pragma unroll
      for (int n = 1; n < 16; ++n) m = fmaxf(m, acc[n][r]);
      m = fmaxf(m, __shfl_xor(m, 1));
      m = fmaxf(m, __shfl_xor(m, 2));
      m = fmaxf(m, __shfl_xor(m, 4));
      m = fmaxf(m, __shfl_xor(m, 8));
      red[r] = m;
    }
    #pragma unroll
    for (int n = 0; n < 16; ++n)
      #pragma unroll
      for (int r = 0; r < 4; ++r)
        acc[n][r] = __expf(acc[n][r] - red[r]);
    #pragma unroll
    for (int r = 0; r < 4; ++r) {
      float s = 0.f;
      #pragma unroll
      for (int n = 0; n < 16; ++n) s += acc[n][r];
      s += __shfl_xor(s, 1); s += __shfl_xor(s, 2);
      s += __shfl_xor(s, 4); s += __shfl_xor(s, 8);
      const float inv = 1.f / s;
      #pragma unroll
      for (int n = 0; n < 16; ++n) acc[n][r] *= inv;
    }
  }
  float* outp = Sreg + (((size_t)zr) << 16) + (size_t)i0 * 256 + cl;
  #pragma unroll
  for (int n = 0; n < 16; ++n)
    #pragma unroll
    for (int r = 0; r < 4; ++r)
      outp[(size_t)r * 256 + n * 16] = acc[n][r];
}

// ---------------------------------------------------------------------------
// Fused flash attention: per 64-row q-tile, stream 64-col k-tiles:
//   s = Q.K^T*SCALE + h   (or Sreg overlay at regional positions)
//   causal online softmax; O += P.V ; final O/l -> ya (B,T,C bf16)
// Block mapping keeps each z's K/V on one XCD: bid%8 == z%8.
// ---------------------------------------------------------------------------
__global__ __launch_bounds__(256)
void flash_k(const u16* __restrict__ Qb, const u16* __restrict__ Kb,
             const u16* __restrict__ Vt, const float* __restrict__ hsrc,
             const float* __restrict__ Sreg, u16* __restrict__ ya)
{
  const int bid = blockIdx.x;          // 0..831
  const int zlow = bid & 7;
  const int t = bid >> 3;              // 0..103
  const int qt = t % 13;
  const int zhigh = t / 13;
  const int z = zhigh * 8 + zlow;
  const int b = z >> 4, hh = z & 15;
  const int q0 = qt * 64;

  const int tid = threadIdx.x;
  const int lane = tid & 63;
  const int wave = tid >> 6;
  const int quad = lane >> 4;
  const int cl = lane & 15;

  __shared__ u16 Qs[2][2048];
  __shared__ u16 Ks[2][2048];
  __shared__ u16 Vs[2][2048];
  __shared__ u16 Ps[4][2][512];

  // ---- stage Q once (two 32-col panels) ----
  {
    const u16* src = Qb + ((size_t)(b * Tn + q0)) * Cn + hh * 64;
    const int r = tid >> 2;
    const int ko = (tid & 3) << 3;
    #pragma unroll
    for (int p = 0; p < 2; ++p)
      __builtin_amdgcn_global_load_lds(
          (__attribute__((address_space(1))) void*)(src + (size_t)r * Cn + p * 32 + ko),
          (__attribute__((address_space(3))) void*)(&Qs[p][wave * 512]), 16, 0, 0);
  }
  __syncthreads();

  bf16x8 qa[2];
  #pragma unroll
  for (int p = 0; p < 2; ++p)
    qa[p] = *(const bf16x8*)(&Qs[p][(wave * 16 + cl) * 32 + quad * 8]);

  f32x4 Oa[4];
  const f32x4 zero4 = {0.f, 0.f, 0.f, 0.f};
  Oa[0] = zero4; Oa[1] = zero4; Oa[2] = zero4; Oa[3] = zero4;
  float mrow[4] = {-3.0e38f, -3.0e38f, -3.0e38f, -3.0e38f};
  float lrow[4] = {0.f, 0.f, 0.f, 0.f};

  const size_t hbase = (size_t)z * Tn * Tn;
  const int qrow_base = q0 + wave * 16 + quad * 4;

  for (int kt = 0; kt <= qt; ++kt) {
    const int k0 = kt * 64;
    __syncthreads();
    {
      const u16* ksrc = Kb + ((size_t)(b * Tn + k0)) * Cn + hh * 64;
      const u16* vsrc = Vt + ((size_t)(z * 64)) * TPn + k0;
      const int r = tid >> 2;
      const int ko = (tid & 3) << 3;
      #pragma unroll
      for (int p = 0; p < 2; ++p) {
        __builtin_amdgcn_global_load_lds(
            (__attribute__((address_space(1))) void*)(ksrc + (size_t)r * Cn + p * 32 + ko),
            (__attribute__((address_space(3))) void*)(&Ks[p][wave * 512]), 16, 0, 0);
        __builtin_amdgcn_global_load_lds(
            (__attribute__((address_space(1))) void*)(vsrc + (size_t)r * TPn + p * 32 + ko),
            (__attribute__((address_space(3))) void*)(&Vs[p][wave * 512]), 16, 0, 0);
      }
    }
    // h / Sreg gather — issued now, in flight with the LDS staging
    float hv[4][4];
    unsigned rmask = 0;
    #pragma unroll
    for (int j = 0; j < 4; ++j) {
      const int kk = k0 + j * 16 + cl;
      #pragma unroll
      for (int r = 0; r < 4; ++r) {
        const int qq = qrow_base + r;
        const float* p = hsrc + hbase + (size_t)qq * Tn + kk;
        bool isreg = false;
        if (kk < 542) {
          if (qq >= 571 && qq < Tn) {
            if (kk < 256) {
              p = Sreg + (((size_t)(z * 3 + 1)) << 16) + (size_t)(qq - 571) * 256 + kk;
              isreg = true;
            } else if (kk >= 286) {
              p = Sreg + (((size_t)(z * 3 + 2)) << 16) + (size_t)(qq - 571) * 256 + (kk - 286);
              isreg = true;
            }
          } else if (qq >= 285 && qq < 541 && kk < 256) {
            p = Sreg + (((size_t)(z * 3 + 0)) << 16) + (size_t)(qq - 285) * 256 + kk;
            isreg = true;
          }
        }
        const bool valid = (kk <= qq) && (qq < Tn);
        hv[j][r] = valid ? *p : 0.f;
        if (isreg) rmask |= 1u << (j * 4 + r);
      }
    }
    __syncthreads();

    // ---- s = Q.K^T ----
    f32x4 sa[4];
    sa[0] = zero4; sa[1] = zero4; sa[2] = zero4; sa[3] = zero4;
    #pragma unroll
    for (int p = 0; p < 2; ++p) {
      #pragma unroll
      for (int n = 0; n < 4; ++n) {
        const bf16x8 kb = *(const bf16x8*)(&Ks[p][(n * 16 + cl) * 32 + quad * 8]);
        sa[n] = __builtin_amdgcn_mfma_f32_16x16x32_bf16(qa[p], kb, sa[n], 0, 0, 0);
      }
    }

    // ---- online softmax rows ----
    #pragma unroll
    for (int r = 0; r < 4; ++r) {
      const int qq = qrow_base + r;
      float sv[4];
      #pragma unroll
      for (int j = 0; j < 4; ++j) {
        const int kk = k0 + j * 16 + cl;
        const float vv = ((rmask >> (j * 4 + r)) & 1)
                             ? hv[j][r]
                             : sa[j][r] * 0.125f + hv[j][r];
        sv[j] = (kk <= qq && qq < Tn) ? vv : -3.0e38f;
      }
      float mx = fmaxf(fmaxf(sv[0], sv[1]), fmaxf(sv[2], sv[3]));
      mx = fmaxf(mx, __shfl_xor(mx, 1));
      mx = fmaxf(mx, __shfl_xor(mx, 2));
      mx = fmaxf(mx, __shfl_xor(mx, 4));
      mx = fmaxf(mx, __shfl_xor(mx, 8));
      const float mnew = fmaxf(mrow[r], mx);
      const float alpha = __expf(mrow[r] - mnew);
      mrow[r] = mnew;
      float ps[4], psum = 0.f;
      #pragma unroll
      for (int j = 0; j < 4; ++j) { ps[j] = __expf(sv[j] - mnew); psum += ps[j]; }
      psum += __shfl_xor(psum, 1);
      psum += __shfl_xor(psum, 2);
      psum += __shfl_xor(psum, 4);
      psum += __shfl_xor(psum, 8);
      lrow[r] = lrow[r] * alpha + psum;
      #pragma unroll
      for (int n = 0; n < 4; ++n) Oa[n][r] *= alpha;
      #pragma unroll
      for (int j = 0; j < 4; ++j)
        Ps[wave][j >> 1][(quad * 4 + r) * 32 + (j & 1) * 16 + cl] = f32_to_bf16(ps[j]);
    }

    // ---- O += P.V ----
    #pragma unroll
    for (int p = 0; p < 2; ++p) {
      const bf16x8 pa = *(const bf16x8*)(&Ps[wave][p][cl * 32 + quad * 8]);
      #pragma unroll
      for (int n = 0; n < 4; ++n) {
        const bf16x8 vb = *(const bf16x8*)(&Vs[p][(n * 16 + cl) * 32 + quad * 8]);
        Oa[n] = __builtin_amdgcn_mfma_f32_16x16x32_bf16(pa, vb, Oa[n], 0, 0, 0);
      }
    }
  }

  // ---- epilogue: ya[b,qq,hh*64+d] = O/l ----
  #pragma unroll
  for (int r = 0; r < 4; ++r) {
    const int qq = qrow_base + r;
    if (qq >= Tn) continue;
    const float inv = 1.f / lrow[r];
    u16* op = ya + ((size_t)(b * Tn + qq)) * Cn + hh * 64;
    #pragma unroll
    for (int n = 0; n < 4; ++n)
      op[n * 16 + cl] = f32_to_bf16(Oa[n][r] * inv);
  }
}

// ---------------------------------------------------------------------------
// bi_epi_ratio[b,i] = sum_h(mask_mean) / sum_h(mean)
// ---------------------------------------------------------------------------
__global__ __launch_bounds__(256)
void ratio_k(const float* __restrict__ mm, const float* __restrict__ am,
             float* __restrict__ out)
{
  const int idx = blockIdx.x * 256 + threadIdx.x;   // 0..1023
  const int b = idx >> 8, i = idx & 255;
  float smm = 0.f, sam = 0.f;
  #pragma unroll
  for (int hh = 0; hh < 16; ++hh) {
    smm += mm[(b * 16 + hh) * 256 + i];
    sam += am[(b * 16 + hh) * 256 + i];
  }
  out[idx] = smm / sam;
}

// ---------------------------------------------------------------------------
extern "C" void kernel_launch(void* const* d_in, const int* in_sizes, int n_in,
                              void* d_out, int out_size, void* d_ws, size_t ws_size,
                              hipStream_t stream)
{
  (void)in_sizes; (void)n_in; (void)out_size;

  const float* x   = (const float*)d_in[0];
  const float* xkv = (const float*)d_in[1];
  const float* hb  = (const float*)d_in[2];   // read-only
  const float* f01 = (const float*)d_in[3];
  const float* f02 = (const float*)d_in[4];
  const float* f12 = (const float*)d_in[5];
  const float* b01 = (const float*)d_in[6];
  const float* b02 = (const float*)d_in[7];
  const float* b12 = (const float*)d_in[8];
  const float* Wq  = (const float*)d_in[9];
  const float* Wk  = (const float*)d_in[10];
  const float* Wv  = (const float*)d_in[11];
  const float* Wp  = (const float*)d_in[12];
  const float* bq  = (const float*)d_in[13];
  const float* bk  = (const float*)d_in[14];
  const float* bv  = (const float*)d_in[15];
  const float* bp  = (const float*)d_in[16];
  float* out = (float*)d_out;

  // ---- workspace layout (unchanged offsets; Vb slot now unused) ----
  char* ws = (char*)d_ws;
  u16* xb   = (u16*)(ws + 0);            //  6,774,784
  u16* xkb  = (u16*)(ws + 6774784);      //  6,774,784
  u16* wqb  = (u16*)(ws + 13549568);     //  2,097,152
  u16* wkb  = (u16*)(ws + 15646720);
  u16* wvb  = (u16*)(ws + 17743872);
  u16* wpb  = (u16*)(ws + 19841024);
  u16* Qb   = (u16*)(ws + 21938176);     //  6,774,784
  u16* Kb   = (u16*)(ws + 28712960);
  // (ws + 35487744) -- former Vb slot, unused
  u16* Vt   = (u16*)(ws + 42262528);     //  6,815,744
  u16* ya   = (u16*)(ws + 49078272);     //  6,774,784
  float* Sreg = (float*)(ws + 55853056); // 50,331,648 (192 x 256 x 256 fp32)
  float* bT = (float*)(ws + 106184704);  //  3,145,728
  float* mm = (float*)(ws + 109330432);  //     65,536
  float* am = (float*)(ws + 109395968);  //     65,536
  const size_t need = 109461504;
  if (ws_size < need) return;            // call-invariant; leaves out poisoned

  // 1) convert inputs/weights to bf16 (+ Vt pad zero); transpose b matrices
  cvt_all_k<<<dim3(10792), 256, 0, stream>>>(x, xkv, Wq, Wk, Wv, Wp,
                                             xb, xkb, wqb, wkb, wvb, wpb, Vt);
  btrans_k<<<dim3(4, 4, 12), 256, 0, stream>>>(b01, b02, b12, bT);
  // 2) fused Q/K/V projections (V written transposed -> Vt directly)
  gemm_qkv_k<<<dim3(26, 8, 3), 256, 0, stream>>>(xb, xkb, wqb, wkb, wvb,
                                                 bq, bk, bv, Qb, Kb, Vt);
  // 3) fused regional scores + softmaxes + stats + multiplies (writes Sreg once)
  regfused_k<<<dim3(4, 192), 256, 0, stream>>>(Qb, Kb, hb, f01, f02, f12, bT,
                                               Sreg, mm, am);
  // 4) bi_epi_ratio -> d_out tail
  ratio_k<<<dim3(4), 256, 0, stream>>>(mm, am, out + YSZ);
  // 5) fused flash attention -> ya
  flash_k<<<dim3(832), 256, 0, stream>>>(Qb, Kb, Vt, hb, Sreg, ya);
  // 6) y = y_att . Wp^T + bp -> d_out (fp32)
  gemm_k<128, 64, 3><<<dim3(26, 16, 1), 256, 0, stream>>>(ya, wpb, bp, out, nullptr,
                                                          BTn, Cn, Cn, Cn, Cn, Cn);
}